// Round 2
// baseline (28.786 us; speedup 1.0000x reference)
//
#include <hip/hip_runtime.h>

// B=8, G=128 gt boxes, A=9 anchors, H=W=64, FEAT_STRIDE=16. K = 36864.
// Output overlaps (B, K, G) fp32 = 151 MB -> pure store-BW bound.
// Ceiling: harness fillBuffer sustains ~6.7 TB/s -> ~22.5 us ideal.
constexpr int G_BOX = 128;
constexpr int N_A   = 9;
constexpr int KTOT  = 64 * 64 * N_A;   // 36864
constexpr int KPQ   = 8;               // k rows per thread
constexpr int NKG   = 8;               // k-groups (of 32 lanes) per block
constexpr int KPB   = KPQ * NKG;       // 64 k rows per block

__global__ __launch_bounds__(256) void overlaps_kernel(
    const float* __restrict__ gt_boxes,   // (B, 128, 5)
    const float* __restrict__ im_info,    // (B, 3) -- ref uses row 0 only
    const float* __restrict__ anchors,    // (9, 4)
    float* __restrict__ out)              // (B, K, G)
{
    __shared__ float s_g[G_BOX][6];       // x1, y1, x2+1, y2+1, area, nz
    __shared__ float s_anc[N_A * 4];

    const int t = threadIdx.x;
    const int b = blockIdx.y;

    if (t < G_BOX) {
        const float* gp = gt_boxes + ((size_t)b * G_BOX + t) * 5;
        float x1 = gp[0], y1 = gp[1], x2 = gp[2], y2 = gp[3];
        float gw = x2 - x1 + 1.0f;
        float gh = y2 - y1 + 1.0f;
        s_g[t][0] = x1;
        s_g[t][1] = y1;
        s_g[t][2] = x2 + 1.0f;
        s_g[t][3] = y2 + 1.0f;
        s_g[t][4] = gw * gh;
        s_g[t][5] = ((gw == 1.0f) && (gh == 1.0f)) ? 0.0f : 1.0f;
    }
    if (t < N_A * 4) s_anc[t] = anchors[t];
    __syncthreads();

    const float im_h = im_info[0];
    const float im_w = im_info[1];

    const int lane = t & 31;              // owns g = 4*lane .. 4*lane+3
    const int kgrp = t >> 5;              // 0..7
    const int k0   = blockIdx.x * KPB + kgrp * KPQ;

    // Hoist this lane's 4 gt boxes into registers (one-time LDS read).
    float gx1[4], gy1[4], gx2p[4], gy2p[4], garea[4], gnz[4];
    #pragma unroll
    for (int j = 0; j < 4; ++j) {
        const float* sg = s_g[4 * lane + j];
        gx1[j] = sg[0]; gy1[j] = sg[1]; gx2p[j] = sg[2];
        gy2p[j] = sg[3]; garea[j] = sg[4]; gnz[j] = sg[5];
    }

    float* outp = out + (((size_t)b * KTOT + k0) * G_BOX + 4 * lane);

    #pragma unroll
    for (int q = 0; q < KPQ; ++q) {
        unsigned k = (unsigned)(k0 + q);
        unsigned a = k % 9u;
        unsigned s = k / 9u;              // spatial index i*64 + j
        float sxv = (float)((s & 63u) * 16u);
        float syv = (float)((s >> 6) * 16u);
        float x1 = s_anc[a * 4 + 0] + sxv;
        float y1 = s_anc[a * 4 + 1] + syv;
        float x2 = s_anc[a * 4 + 2] + sxv;
        float y2 = s_anc[a * 4 + 3] + syv;
        float aw = x2 - x1 + 1.0f;
        float ah = y2 - y1 + 1.0f;
        float ax2p = x2 + 1.0f;
        float ay2p = y2 + 1.0f;
        float aarea = aw * ah;
        bool a_zero = (aw == 1.0f) && (ah == 1.0f);
        bool inside = (x1 >= 0.0f) && (y1 >= 0.0f) && (x2 < im_w) && (y2 < im_h);
        bool sel = a_zero || !inside;     // -> -1 regardless of IoU

        float4 v;
        float* vp = &v.x;
        #pragma unroll
        for (int j = 0; j < 4; ++j) {
            float ix1  = fmaxf(x1, gx1[j]);
            float iy1  = fmaxf(y1, gy1[j]);
            float ix2p = fminf(ax2p, gx2p[j]);   // = min(x2,gx2)+1 exactly
            float iy2p = fminf(ay2p, gy2p[j]);
            float iw = fmaxf(ix2p - ix1, 0.0f);
            float ih = fmaxf(iy2p - iy1, 0.0f);
            float inter = iw * ih;
            float ua = aarea + garea[j] - inter; // > 0 for this data
            float r = inter * __builtin_amdgcn_rcpf(ua);
            r *= gnz[j];                          // gt_zero -> 0
            vp[j] = sel ? -1.0f : r;
        }
        // 32 lanes x 16B = contiguous 512B per k-row; q folds into imm offset.
        *reinterpret_cast<float4*>(outp + (size_t)q * G_BOX) = v;
    }
}

extern "C" void kernel_launch(void* const* d_in, const int* in_sizes, int n_in,
                              void* d_out, int out_size, void* d_ws, size_t ws_size,
                              hipStream_t stream) {
    // inputs: 0=rpn_cls_score (unused), 1=gt_boxes, 2=im_info,
    //         3=num_boxes (unused by reference output), 4=anchors
    const float* gt_boxes = (const float*)d_in[1];
    const float* im_info  = (const float*)d_in[2];
    const float* anchors  = (const float*)d_in[4];
    float* out = (float*)d_out;

    dim3 grid(KTOT / KPB, 8);   // (576, 8)
    dim3 block(256);
    overlaps_kernel<<<grid, block, 0, stream>>>(gt_boxes, im_info, anchors, out);
}